// Round 3
// baseline (3350.611 us; speedup 1.0000x reference)
//
#include <hip/hip_runtime.h>
#include <math.h>

#define NMAT 240
#define NFULL 256
#define NG (NMAT*NMAT)          // 57600
#define ITERS 30
#define NB 241                  // 240 row blocks + 1 tau block (<= 256 CUs -> all co-resident)
#define ORD_SCALE (1.0f/61440.0f)
#define C4 15                   // float4 iterations per chunk (60 elems / 4)

// Persistent device state (re-initialized every kernel_launch call)
__device__ __align__(16) float4 g_Bq4[NG/4];  // [k4*240+j].{x,y,z,w} = B[j, 4*k4+{0..3}]
__device__ __align__(16) float4 g_Aq4[NG/4];  // [w4*240+j].{x,y,z,w} = B[4*w4+{0..3}, j]
__device__ __align__(16) float g_S[2][NG];    // ping-pong sigmoid(Gl) (only tau block reads)
__device__ float g_tau[2][NFULL];
__device__ float g_acc[2];
__device__ unsigned g_count, g_gen;

__device__ __forceinline__ float sigm(float x) { return 1.0f / (1.0f + expf(-x)); }

// Sense-reversal grid barrier. Safe because all NB=241 blocks are co-resident
// (241 <= 256 CUs; one 16-wave block per CU). Device-scope atomics + fences
// handle cross-XCD L2 visibility.
__device__ __forceinline__ void grid_barrier()
{
    __syncthreads();
    if (threadIdx.x == 0) {
        __threadfence();  // release prior writes (device scope)
        unsigned gen = __hip_atomic_load(&g_gen, __ATOMIC_RELAXED, __HIP_MEMORY_SCOPE_AGENT);
        unsigned my  = __hip_atomic_fetch_add(&g_count, 1u, __ATOMIC_ACQ_REL, __HIP_MEMORY_SCOPE_AGENT);
        if (my == NB - 1) {
            __hip_atomic_store(&g_count, 0u, __ATOMIC_RELAXED, __HIP_MEMORY_SCOPE_AGENT);
            __hip_atomic_fetch_add(&g_gen, 1u, __ATOMIC_RELEASE, __HIP_MEMORY_SCOPE_AGENT);
        } else {
            while (__hip_atomic_load(&g_gen, __ATOMIC_ACQUIRE, __HIP_MEMORY_SCOPE_AGENT) == gen)
                __builtin_amdgcn_s_sleep(1);
        }
        __threadfence();  // acquire side
    }
    __syncthreads();
}

__global__ void k_init(const float* __restrict__ A, const float* __restrict__ tau0)
{
    int idx = blockIdx.x * 256 + threadIdx.x;
    if (idx < NG) {
        int r = idx / NMAT;            // k (for Bq) / w (for Aq)
        int j = idx - r * NMAT;
        // Bq: B[j,k] = A[j*256 + 16 + k]
        ((float*)g_Bq4)[(r >> 2) * (NMAT * 4) + j * 4 + (r & 3)] = A[j * NFULL + 16 + r];
        // Aq: B[w,j] = A[w*256 + 16 + j]
        ((float*)g_Aq4)[(r >> 2) * (NMAT * 4) + j * 4 + (r & 3)] = A[r * NFULL + 16 + j];
    }
    if (idx < NFULL) g_tau[0][idx] = tau0[idx];
    if (idx == 0) { g_acc[0] = 0.f; g_acc[1] = 0.f; g_count = 0u; g_gen = 0u; }
}

// Persistent kernel: 30 Adam iterations + final loss, one launch.
// Blocks 0..239: row u (Gl[u,:] state in registers of c==0 threads, S row in LDS).
// Block 240: tau (state in registers of tid<256 threads, tau in LDS).
__global__ __launch_bounds__(1024) void k_main(const float* __restrict__ Gl0,
                                               float* __restrict__ out)
{
    const int tid = threadIdx.x;
    const int c = tid >> 8;          // chunk 0..3
    const int j = tid & 255;         // lane 0..255
    const int u = blockIdx.x;

    __shared__ __align__(16) float sl2[NMAT];    // -2 * S[u,:]
    __shared__ __align__(16) float wl[NMAT];     // W[u,:]
    __shared__ float tl[NFULL];                  // tau (row: current read; tau block: live)
    __shared__ __align__(16) float pp[4][256];
    __shared__ __align__(16) float ap[4][256];
    __shared__ float red[8];

    // persistent per-thread Adam state
    float gl = 0.f, am = 0.f, av = 0.f, sc = 0.f;   // row blocks, c==0
    float tm = 0.f, tv = 0.f;                        // tau block, tid<256
    double b1p = 1.0, b2p = 1.0;

    if (u < NMAT) {
        if (c == 0 && j < NMAT) {
            gl = Gl0[u * NMAT + j];
            sc = sigm(gl);
            sl2[j] = -2.0f * sc;
            g_S[0][u * NMAT + j] = sc;   // publish S_0 for tau block
        }
    } else {
        if (tid < NFULL) tl[tid] = g_tau[0][tid];
    }
    grid_barrier();

    for (int t = 0; t < ITERS; ++t) {
        const int par = t & 1;
        b1p *= 0.9; b2p *= 0.999;
        const float bc1 = (float)(1.0 - b1p);
        const float bc2 = (float)(1.0 - b2p);

        if (u < NMAT) {
            // ---- row block ----
            if (tid < NFULL) tl[tid] = g_tau[par][tid];
            // Phase A: partial products over k-chunk (4 independent chains)
            float p0 = 1.f, p1 = 1.f, p2 = 1.f, p3 = 1.f;
            if (j < NMAT) {
                const float4* slv = (const float4*)sl2;
                #pragma unroll
                for (int i = 0; i < C4; ++i) {
                    const int k4 = c * C4 + i;
                    float4 b = g_Bq4[k4 * NMAT + j];
                    float4 s = slv[k4];
                    p0 *= fmaf(s.x, b.x, 1.0f);
                    p1 *= fmaf(s.y, b.y, 1.0f);
                    p2 *= fmaf(s.z, b.z, 1.0f);
                    p3 *= fmaf(s.w, b.w, 1.0f);
                }
            }
            pp[c][j] = (p0 * p1) * (p2 * p3);
            __syncthreads();
            if (c == 0 && j < NMAT) {
                float pr = (pp[0][j] * pp[1][j]) * (pp[2][j] * pp[3][j]);
                float tt = (j == u) ? -1.0f : 1.0f;
                wl[j] = (pr - tt) * pr;
            }
            __syncthreads();
            // Phase B: grad accumulation over w-chunk
            float a0 = 0.f, a1 = 0.f, a2 = 0.f, a3 = 0.f;
            if (j < NMAT) {
                const float s2 = sl2[j];
                const float4* wlv = (const float4*)wl;
                #pragma unroll
                for (int i = 0; i < C4; ++i) {
                    const int w4 = c * C4 + i;
                    float4 b = g_Aq4[w4 * NMAT + j];
                    float4 w = wlv[w4];
                    float t0 = fmaf(s2, b.x, 1.0f);
                    float t1 = fmaf(s2, b.y, 1.0f);
                    float t2 = fmaf(s2, b.z, 1.0f);
                    float t3 = fmaf(s2, b.w, 1.0f);
                    a0 += (t0 != 0.0f) ? w.x * b.x * __builtin_amdgcn_rcpf(t0) : 0.0f;
                    a1 += (t1 != 0.0f) ? w.y * b.y * __builtin_amdgcn_rcpf(t1) : 0.0f;
                    a2 += (t2 != 0.0f) ? w.z * b.z * __builtin_amdgcn_rcpf(t2) : 0.0f;
                    a3 += (t3 != 0.0f) ? w.w * b.w * __builtin_amdgcn_rcpf(t3) : 0.0f;
                }
            }
            ap[c][j] = (a0 + a1) + (a2 + a3);
            __syncthreads();
            if (c == 0 && j < NMAT) {
                float a4 = (ap[0][j] + ap[1][j]) + (ap[2][j] + ap[3][j]);
                float g_odd = -a4 * (1.0f / 240.0f);
                float d = tl[u] - tl[16 + j] + 0.1f;
                float r = fmaxf(d, 0.0f);
                float gS = g_odd + r * r * ORD_SCALE;
                float gGl = gS * sc * (1.0f - sc);
                am = 0.9f * am + 0.1f * gGl;
                av = 0.999f * av + 0.001f * gGl * gGl;
                gl -= 0.1f * (am / bc1) / (sqrtf(av / bc2) + 1e-8f);
                sc = sigm(gl);
                sl2[j] = -2.0f * sc;
                g_S[par ^ 1][u * NMAT + j] = sc;   // publish for tau block
            }
        } else {
            // ---- tau block ----
            const float* __restrict__ S_in = g_S[par];
            float cs = 0.f, rs = 0.f;
            if (j >= 16) {
                const int jj = j - 16;
                const float tj = tl[j];
                #pragma unroll
                for (int q = 0; q < 60; ++q) {
                    const int i = c * 60 + q;
                    float d = tl[i] - tj + 0.1f;
                    float r = fmaxf(d, 0.0f);
                    cs += S_in[i * NMAT + jj] * (2.0f * r);  // coalesced across j
                }
            }
            if (j < NMAT) {
                const float tj = tl[j];
                const float4* srow = (const float4*)(S_in + j * NMAT);  // 960B row stride, 16B aligned
                #pragma unroll
                for (int i = 0; i < C4; ++i) {
                    const int q4 = c * C4 + i;
                    float4 s = srow[q4];
                    const int q = q4 * 4;
                    float r0 = fmaxf(tj - tl[16 + q + 0] + 0.1f, 0.f);
                    float r1 = fmaxf(tj - tl[16 + q + 1] + 0.1f, 0.f);
                    float r2 = fmaxf(tj - tl[16 + q + 2] + 0.1f, 0.f);
                    float r3 = fmaxf(tj - tl[16 + q + 3] + 0.1f, 0.f);
                    rs += s.x * (2.f * r0) + s.y * (2.f * r1) + s.z * (2.f * r2) + s.w * (2.f * r3);
                }
            }
            pp[c][j] = cs; ap[c][j] = rs;
            __syncthreads();
            if (c == 0) {
                float csum = (j >= 16)  ? ((pp[0][j] + pp[1][j]) + (pp[2][j] + pp[3][j])) : 0.0f;
                float rsum = (j < NMAT) ? ((ap[0][j] + ap[1][j]) + (ap[2][j] + ap[3][j])) : 0.0f;
                float g = (rsum - csum) * ORD_SCALE;
                tm = 0.9f * tm + 0.1f * g;
                tv = 0.999f * tv + 0.001f * g * g;
                float tnew = tl[j] - 0.1f * (tm / bc1) / (sqrtf(tv / bc2) + 1e-8f);
                g_tau[par ^ 1][j] = tnew;   // publish for row blocks
                tl[j] = tnew;               // own read of tl[j] already done
            }
        }
        grid_barrier();
    }

    // ---- final loss (params at parity 0; sl2/sc hold final S) ----
    if (u < NMAT) {
        float p0 = 1.f, p1 = 1.f, p2 = 1.f, p3 = 1.f;
        if (j < NMAT) {
            const float4* slv = (const float4*)sl2;
            #pragma unroll
            for (int i = 0; i < C4; ++i) {
                const int k4 = c * C4 + i;
                float4 b = g_Bq4[k4 * NMAT + j];
                float4 s = slv[k4];
                p0 *= fmaf(s.x, b.x, 1.0f);
                p1 *= fmaf(s.y, b.y, 1.0f);
                p2 *= fmaf(s.z, b.z, 1.0f);
                p3 *= fmaf(s.w, b.w, 1.0f);
            }
        }
        pp[c][j] = (p0 * p1) * (p2 * p3);
        __syncthreads();
        float odd = 0.f, ord = 0.f;
        if (c == 0 && j < NMAT) {
            float pr = (pp[0][j] * pp[1][j]) * (pp[2][j] * pp[3][j]);
            float tt = (j == u) ? -1.0f : 1.0f;
            float r = pr - tt;
            odd = r * r;
            float d = g_tau[0][u] - g_tau[0][16 + j] + 0.1f;
            float rr = fmaxf(d, 0.0f);
            ord = sc * rr * rr;
        }
        for (int off = 32; off > 0; off >>= 1) {
            odd += __shfl_down(odd, off);
            ord += __shfl_down(ord, off);
        }
        if (tid < 256 && (tid & 63) == 0) { red[(tid >> 6) * 2] = odd; red[(tid >> 6) * 2 + 1] = ord; }
        __syncthreads();
        if (tid == 0) {
            atomicAdd(&g_acc[0], (red[0] + red[2]) + (red[4] + red[6]));
            atomicAdd(&g_acc[1], (red[1] + red[3]) + (red[5] + red[7]));
        }
    }
    grid_barrier();
    if (u == 0 && tid == 0)
        out[0] = g_acc[0] * (1.0f / 960.0f) + g_acc[1] * (1.0f / 61440.0f);
}

extern "C" void kernel_launch(void* const* d_in, const int* in_sizes, int n_in,
                              void* d_out, int out_size, void* d_ws, size_t ws_size,
                              hipStream_t stream)
{
    const float* A    = (const float*)d_in[0];
    const float* Gl0  = (const float*)d_in[1];
    const float* tau0 = (const float*)d_in[2];
    float* out = (float*)d_out;

    k_init<<<(NG + 255) / 256, 256, 0, stream>>>(A, tau0);
    k_main<<<NB, 1024, 0, stream>>>(Gl0, out);
}

// Round 4
// 384.724 us; speedup vs baseline: 8.7091x; 8.7091x over previous
//
#include <hip/hip_runtime.h>
#include <math.h>

#define NMAT 240
#define NFULL 256
#define NG (NMAT*NMAT)          // 57600
#define ITERS 30
#define ORD_SCALE (1.0f/61440.0f)
#define C4 15                   // float4 iterations per chunk (60 elems / 4)

// Persistent device state (fully re-initialized by k_init every call)
__device__ __align__(16) float4 g_Bq4[NG/4];  // [k4*240+j].{x..w} = B[j, 4*k4+{0..3}]
__device__ __align__(16) float4 g_Aq4[NG/4];  // [w4*240+j].{x..w} = B[4*w4+{0..3}, j]
__device__ __align__(16) float g_S[2][NG];    // ping-pong sigmoid(Gl)
__device__ float g_Gl[NG], g_mG[NG], g_vG[NG];
__device__ float g_tau[2][NFULL], g_mT[NFULL], g_vT[NFULL];
__device__ float g_acc[2];

__device__ __forceinline__ float sigm(float x) { return 1.0f / (1.0f + expf(-x)); }

__global__ void k_init(const float* __restrict__ A,
                       const float* __restrict__ Gl0,
                       const float* __restrict__ tau0)
{
    int idx = blockIdx.x * 256 + threadIdx.x;
    if (idx < NG) {
        int r = idx / NMAT;            // k (for Bq) / w (for Aq)
        int j = idx - r * NMAT;
        // Bq: B[j,k] = A[j*256 + 16 + k]
        ((float*)g_Bq4)[(r >> 2) * (NMAT * 4) + j * 4 + (r & 3)] = A[j * NFULL + 16 + r];
        // Aq: B[w,j] = A[w*256 + 16 + j]
        ((float*)g_Aq4)[(r >> 2) * (NMAT * 4) + j * 4 + (r & 3)] = A[r * NFULL + 16 + j];
        float g = Gl0[idx];
        g_Gl[idx] = g;
        g_mG[idx] = 0.f; g_vG[idx] = 0.f;
        g_S[0][idx] = sigm(g);
    }
    if (idx < NFULL) {
        g_tau[0][idx] = tau0[idx];
        g_mT[idx] = 0.f; g_vT[idx] = 0.f;
    }
    if (idx < 2) g_acc[idx] = 0.f;
}

// One inner-opt iteration, fused.
// blocks 0..239 (row u): P[u,:] -> W[u,:] (LDS) -> dL/dGl[u,:] -> Adam -> S_out[u,:]
// block 240: tau grad + Adam -> tau_out
// 1024 threads = 4 chunks (c) x 256 lanes (j); 240-deep loops split 4 x (15 float4).
__global__ __launch_bounds__(1024) void k_iter(int par, float bc1, float bc2)
{
    const int tid = threadIdx.x;
    const int c = tid >> 8;          // chunk 0..3
    const int j = tid & 255;         // lane 0..255
    const float* __restrict__ S_in  = g_S[par];
    const float* __restrict__ tauin = g_tau[par];

    if (blockIdx.x == NMAT) {
        // ---- tau update ----
        __shared__ float tl[NFULL];
        __shared__ float cpart[4][NFULL];
        __shared__ float rpart[4][NFULL];
        if (tid < NFULL) tl[tid] = tauin[tid];
        __syncthreads();
        float cs = 0.f, rs = 0.f;
        if (j >= 16) {
            const int jj = j - 16;
            const float tj = tl[j];
            #pragma unroll
            for (int q = 0; q < 60; ++q) {
                const int i = c * 60 + q;
                float d = tl[i] - tj + 0.1f;
                float r = fmaxf(d, 0.0f);
                cs += S_in[i * NMAT + jj] * (2.0f * r);   // coalesced across j
            }
        }
        if (j < NMAT) {
            const float tj = tl[j];
            const float4* srow = (const float4*)(S_in + j * NMAT);  // 960B stride, 16B aligned
            #pragma unroll
            for (int i = 0; i < C4; ++i) {
                const int q4 = c * C4 + i;
                float4 s = srow[q4];
                const int q = q4 * 4;
                float r0 = fmaxf(tj - tl[16 + q + 0] + 0.1f, 0.f);
                float r1 = fmaxf(tj - tl[16 + q + 1] + 0.1f, 0.f);
                float r2 = fmaxf(tj - tl[16 + q + 2] + 0.1f, 0.f);
                float r3 = fmaxf(tj - tl[16 + q + 3] + 0.1f, 0.f);
                rs += s.x * (2.f * r0) + s.y * (2.f * r1) + s.z * (2.f * r2) + s.w * (2.f * r3);
            }
        }
        cpart[c][j] = cs; rpart[c][j] = rs;
        __syncthreads();
        if (c == 0) {
            float csum = (cpart[0][j] + cpart[1][j]) + (cpart[2][j] + cpart[3][j]);
            float rsum = (rpart[0][j] + rpart[1][j]) + (rpart[2][j] + rpart[3][j]);
            float g = (rsum - csum) * ORD_SCALE;
            float m = 0.9f * g_mT[j] + 0.1f * g;
            float v = 0.999f * g_vT[j] + 0.001f * g * g;
            g_mT[j] = m; g_vT[j] = v;
            g_tau[par ^ 1][j] = tl[j] - 0.1f * (m / bc1) / (sqrtf(v / bc2) + 1e-8f);
        }
        return;
    }

    // ---- row u: fused prod + grad + Adam ----
    const int u = blockIdx.x;
    __shared__ __align__(16) float sl2[NMAT];    // -2 * S[u,:]
    __shared__ __align__(16) float wl[NMAT];     // W[u,:]
    __shared__ __align__(16) float pp[4][256];
    __shared__ __align__(16) float ap[4][256];
    if (tid < NMAT) sl2[tid] = -2.0f * S_in[u * NMAT + tid];
    __syncthreads();

    // Phase A: partial products over k-chunk; 15 independent dwordx4 loads
    float p0 = 1.f, p1 = 1.f, p2 = 1.f, p3 = 1.f;
    if (j < NMAT) {
        const float4* slv = (const float4*)sl2;
        #pragma unroll
        for (int i = 0; i < C4; ++i) {
            const int k4 = c * C4 + i;
            float4 b = g_Bq4[k4 * NMAT + j];
            float4 s = slv[k4];
            p0 *= fmaf(b.x, s.x, 1.0f);
            p1 *= fmaf(b.y, s.y, 1.0f);
            p2 *= fmaf(b.z, s.z, 1.0f);
            p3 *= fmaf(b.w, s.w, 1.0f);
        }
    }
    pp[c][j] = (p0 * p1) * (p2 * p3);
    __syncthreads();
    if (c == 0 && j < NMAT) {
        float pr = (pp[0][j] * pp[1][j]) * (pp[2][j] * pp[3][j]);
        float tt = (j == u) ? -1.0f : 1.0f;
        wl[j] = (pr - tt) * pr;
    }
    __syncthreads();

    // Phase B: grad accumulation over w-chunk; 15 independent dwordx4 loads
    float a0 = 0.f, a1 = 0.f, a2 = 0.f, a3 = 0.f;
    const float s2 = (j < NMAT) ? sl2[j] : 0.f;
    if (j < NMAT) {
        const float4* wlv = (const float4*)wl;
        #pragma unroll
        for (int i = 0; i < C4; ++i) {
            const int w4 = c * C4 + i;
            float4 b = g_Aq4[w4 * NMAT + j];
            float4 w = wlv[w4];
            float t0 = fmaf(b.x, s2, 1.0f);
            float t1 = fmaf(b.y, s2, 1.0f);
            float t2 = fmaf(b.z, s2, 1.0f);
            float t3 = fmaf(b.w, s2, 1.0f);
            a0 += (t0 != 0.0f) ? w.x * b.x * __builtin_amdgcn_rcpf(t0) : 0.0f;
            a1 += (t1 != 0.0f) ? w.y * b.y * __builtin_amdgcn_rcpf(t1) : 0.0f;
            a2 += (t2 != 0.0f) ? w.z * b.z * __builtin_amdgcn_rcpf(t2) : 0.0f;
            a3 += (t3 != 0.0f) ? w.w * b.w * __builtin_amdgcn_rcpf(t3) : 0.0f;
        }
    }
    ap[c][j] = (a0 + a1) + (a2 + a3);
    __syncthreads();

    if (c == 0 && j < NMAT) {
        float a4 = (ap[0][j] + ap[1][j]) + (ap[2][j] + ap[3][j]);
        float g_odd = -a4 * (1.0f / 240.0f);
        float d = tauin[u] - tauin[16 + j] + 0.1f;
        float r = fmaxf(d, 0.0f);
        float sc = -0.5f * s2;                      // S[u,j]
        float gS = g_odd + r * r * ORD_SCALE;
        float gGl = gS * sc * (1.0f - sc);          // sigmoid'
        const int idx = u * NMAT + j;
        float m = 0.9f * g_mG[idx] + 0.1f * gGl;
        float v = 0.999f * g_vG[idx] + 0.001f * gGl * gGl;
        g_mG[idx] = m; g_vG[idx] = v;
        float pnew = g_Gl[idx] - 0.1f * (m / bc1) / (sqrtf(v / bc2) + 1e-8f);
        g_Gl[idx] = pnew;
        g_S[par ^ 1][idx] = sigm(pnew);
    }
}

// Final loss: block u covers row u of L_odd and L_order
__global__ __launch_bounds__(1024) void k_final(int par)
{
    __shared__ __align__(16) float sl2[NMAT];
    __shared__ __align__(16) float pp[4][256];
    __shared__ float rodd[4], rord[4];
    const int u = blockIdx.x, tid = threadIdx.x;
    const int c = tid >> 8, j = tid & 255;
    const float* __restrict__ S   = g_S[par];
    const float* __restrict__ tau = g_tau[par];
    if (tid < NMAT) sl2[tid] = -2.0f * S[u * NMAT + tid];
    __syncthreads();

    float p0 = 1.f, p1 = 1.f, p2 = 1.f, p3 = 1.f;
    if (j < NMAT) {
        const float4* slv = (const float4*)sl2;
        #pragma unroll
        for (int i = 0; i < C4; ++i) {
            const int k4 = c * C4 + i;
            float4 b = g_Bq4[k4 * NMAT + j];
            float4 s = slv[k4];
            p0 *= fmaf(b.x, s.x, 1.0f);
            p1 *= fmaf(b.y, s.y, 1.0f);
            p2 *= fmaf(b.z, s.z, 1.0f);
            p3 *= fmaf(b.w, s.w, 1.0f);
        }
    }
    pp[c][j] = (p0 * p1) * (p2 * p3);
    __syncthreads();

    float odd = 0.f, ord = 0.f;
    if (c == 0 && j < NMAT) {
        float pr = (pp[0][j] * pp[1][j]) * (pp[2][j] * pp[3][j]);
        float tt = (j == u) ? -1.0f : 1.0f;
        float r = pr - tt;
        odd = r * r;
        float d = tau[u] - tau[16 + j] + 0.1f;
        float rr = fmaxf(d, 0.0f);
        ord = (-0.5f * sl2[j]) * rr * rr;
    }
    for (int off = 32; off > 0; off >>= 1) {
        odd += __shfl_down(odd, off);
        ord += __shfl_down(ord, off);
    }
    int lane = tid & 63, wv = tid >> 6;
    if (lane == 0 && wv < 4) { rodd[wv] = odd; rord[wv] = ord; }
    __syncthreads();
    if (tid == 0) {
        float so = (rodd[0] + rodd[1]) + (rodd[2] + rodd[3]);
        float sr = (rord[0] + rord[1]) + (rord[2] + rord[3]);
        atomicAdd(&g_acc[0], so);
        atomicAdd(&g_acc[1], sr);
    }
}

__global__ void k_out(float* __restrict__ out)
{
    out[0] = g_acc[0] * (1.0f / 960.0f) + g_acc[1] * (1.0f / 61440.0f);
}

extern "C" void kernel_launch(void* const* d_in, const int* in_sizes, int n_in,
                              void* d_out, int out_size, void* d_ws, size_t ws_size,
                              hipStream_t stream)
{
    const float* A    = (const float*)d_in[0];
    const float* Gl0  = (const float*)d_in[1];
    const float* tau0 = (const float*)d_in[2];
    float* out = (float*)d_out;

    k_init<<<(NG + 255) / 256, 256, 0, stream>>>(A, Gl0, tau0);

    for (int t = 0; t < ITERS; ++t) {
        int par = t & 1;
        double tt = (double)(t + 1);
        float bc1 = (float)(1.0 - pow((double)0.9f,   tt));
        float bc2 = (float)(1.0 - pow((double)0.999f, tt));
        k_iter<<<NMAT + 1, 1024, 0, stream>>>(par, bc1, bc2);
    }
    // after 30 iterations final params live in parity 0
    k_final<<<NMAT, 1024, 0, stream>>>(0);
    k_out<<<1, 1, 0, stream>>>(out);
}